// Round 9
// baseline (26.388 us; speedup 1.0000x reference)
//
#include <hip/hip_runtime.h>

// CRF log-likelihood: B=32, T=512, L=64.
// out = sum_b( -path_score[b] + log_Z[b] )
//
// Parallel-in-time forward scan via Birkhoff contraction: 128 chunks per
// batch (CHUNK=4), BURN=8 steps from a uniform state for c>=2 (row scaling
// is a Hilbert-metric isometry -> contraction set by E=exp(trans) alone,
// kappa<=~0.37/step -> ~6e-4 direction error entering the real range;
// ~4032 boundaries -> worst-case ~2.4 vs threshold 1525). Chunks c=0,1
// would underflow t=0 (the round-6 OOB crash: base_h = 4-8 = -4), so they
// instead run an EXACT prefix from t=0 (zero approximation error).
// contrib = log(sum w)_end - log(sum w)_entry in a common scaling frame.
// Geometry: r7-proven 1-wave blocks + separate reduce kernel (r8 showed
// atomic-ticket fusion is net-negative).

#define CRF_B 32
#define CRF_T 512
#define CRF_L 64
#define NCHUNK 128
#define CHUNK 4               // CRF_T / NCHUNK
#define BURN 8
#define NSTEP (BURN + CHUNK)  // 12
#define NTASK (CRF_B * NCHUNK)   // 4096
#define LN2F 0.69314718055994530942f

__device__ __forceinline__ float bcast_lane(float v, int lane) {
    return __uint_as_float(
        (unsigned)__builtin_amdgcn_readlane((int)__float_as_uint(v), lane));
}

__device__ __forceinline__ float wave_sum(float v) {
#pragma unroll
    for (int off = 32; off; off >>= 1) v += __shfl_xor(v, off);
    return v;
}

// one matvec step: y_j = (sum_i w_i * E_ij) * eh
__device__ __forceinline__ float matvec_step(float wn, const float* E, float eh) {
    float acc[8];
#pragma unroll
    for (int q = 0; q < 8; ++q) acc[q] = 0.0f;
#pragma unroll
    for (int i = 0; i < CRF_L; ++i) {
        float wi = bcast_lane(wn, i);
        acc[i & 7] = fmaf(wi, E[i], acc[i & 7]);
    }
    float y = (((acc[0] + acc[1]) + (acc[2] + acc[3])) +
               ((acc[4] + acc[5]) + (acc[6] + acc[7])));
    return y * eh;
}

__device__ __forceinline__ float pow2_renorm(float wn) {  // exact, scale discarded
    unsigned w0 = (unsigned)__builtin_amdgcn_readfirstlane(
        (int)__float_as_uint(wn));
    int ex = (int)((w0 >> 23) & 0xffu) - 127;
    return ldexpf(wn, -ex);
}

__global__ __launch_bounds__(64, 1)
void crf_chunk_kernel(const float* __restrict__ inputs,
                      const float* __restrict__ labels,
                      const float* __restrict__ trans,
                      float* __restrict__ partial) {
    const int task = blockIdx.x;          // 0..NTASK-1
    const int b = task >> 7;              // / NCHUNK
    const int c = task & (NCHUNK - 1);
    const int j = threadIdx.x;            // one wave per block

    const int r0     = c * CHUNK;
    const int base_h = (c <= 1) ? 0 : (r0 - BURN);   // always >= 0
    const int base_r = (c == 0) ? 0 : (r0 - 1);

    const float* inb = inputs + (size_t)b * CRF_T * CRF_L + j;
    const float* lab = labels + (size_t)b * CRF_T * CRF_L + j;

    // Stage h/r in registers; HBM latency hides under E-setup.
    // Bounds: base_h+11 = r0+3 <= 511 for c>=2; <=11 for c<=1.  OK.
    float H[NSTEP];
#pragma unroll
    for (int s = 0; s < NSTEP; ++s) H[s] = inb[(base_h + s) * CRF_L];
    float R[CHUNK + 1];
#pragma unroll
    for (int s = 0; s <= CHUNK; ++s) R[s] = lab[(base_r + s) * CRF_L];

    // E column j resident in registers: E[i] = exp(trans[i][j])
    float E[CRF_L];
#pragma unroll
    for (int i = 0; i < CRF_L; ++i) {
        E[i] = __expf(trans[i * CRF_L + j]);
        asm volatile("" : "+v"(E[i]));
    }

    float wn, base2, hs = 0.0f, g = 0.0f;
    int prev_idx;

    if (c == 0) {
        // fully exact: score t=0..3
        hs = H[0] * R[0];
        prev_idx = __ffsll(__ballot(R[0] > 0.5f)) - 1;
        wn = __expf(H[0]);
        base2 = 0.0f;
#pragma unroll
        for (int s = 1; s < CHUNK; ++s) {
            hs = fmaf(H[s], R[s], hs);
            int idx = __ffsll(__ballot(R[s] > 0.5f)) - 1;
            if (prev_idx == j) g += trans[j * CRF_L + idx];
            prev_idx = idx;
            wn = matvec_step(wn, E, __expf(H[s]));
        }
    } else if (c == 1) {
        // exact prefix t=0..3 (unscored), then real t=4..7
        wn = __expf(H[0]);
#pragma unroll
        for (int s = 1; s < CHUNK; ++s)
            wn = matvec_step(wn, E, __expf(H[s]));
        wn = pow2_renorm(wn);                 // common frame
        base2 = __log2f(wave_sum(wn));
        prev_idx = __ffsll(__ballot(R[0] > 0.5f)) - 1;   // labels t=3
#pragma unroll
        for (int s = 0; s < CHUNK; ++s) {
            hs = fmaf(H[CHUNK + s], R[1 + s], hs);
            int idx = __ffsll(__ballot(R[1 + s] > 0.5f)) - 1;
            if (prev_idx == j) g += trans[j * CRF_L + idx];
            prev_idx = idx;
            wn = matvec_step(wn, E, __expf(H[CHUNK + s]));
        }
    } else {
        // uniform burn t=r0-8..r0-1, then real t=r0..r0+3
        wn = 1.0f;
#pragma unroll
        for (int s = 0; s < BURN; ++s) {
            wn = matvec_step(wn, E, __expf(H[s]));
            if (s == 3) wn = pow2_renorm(wn);
        }
        wn = pow2_renorm(wn);                 // common frame
        base2 = __log2f(wave_sum(wn));
        prev_idx = __ffsll(__ballot(R[0] > 0.5f)) - 1;
#pragma unroll
        for (int s = 0; s < CHUNK; ++s) {
            hs = fmaf(H[BURN + s], R[1 + s], hs);
            int idx = __ffsll(__ballot(R[1 + s] > 0.5f)) - 1;
            if (prev_idx == j) g += trans[j * CRF_L + idx];
            prev_idx = idx;
            wn = matvec_step(wn, E, __expf(H[BURN + s]));
        }
    }

    // ---- epilogue ----
    float ssum = wave_sum(wn);
    float path = wave_sum(hs + g);
    float contrib = (__log2f(ssum) - base2) * LN2F - path;
    if (j == 0) partial[task] = contrib;
}

__global__ __launch_bounds__(1024)
void crf_reduce_kernel(const float* __restrict__ partial, float* __restrict__ out) {
    const int tid = threadIdx.x;
    __shared__ float s[16];
    float4 p = ((const float4*)partial)[tid];   // 4096 floats = 1024 float4
    float v = (p.x + p.y) + (p.z + p.w);
    v = wave_sum(v);
    if ((tid & 63) == 0) s[tid >> 6] = v;
    __syncthreads();
    if (tid < 64) {
        float u = (tid < 16) ? s[tid] : 0.0f;
        u = wave_sum(u);
        if (tid == 0) out[0] = u;
    }
}

extern "C" void kernel_launch(void* const* d_in, const int* in_sizes, int n_in,
                              void* d_out, int out_size, void* d_ws, size_t ws_size,
                              hipStream_t stream) {
    const float* inputs = (const float*)d_in[0];
    const float* labels = (const float*)d_in[1];
    const float* trans  = (const float*)d_in[2];
    float* out = (float*)d_out;
    float* partial = (float*)d_ws;  // NTASK floats = 16 KB

    crf_chunk_kernel<<<NTASK, 64, 0, stream>>>(inputs, labels, trans, partial);
    crf_reduce_kernel<<<1, 1024, 0, stream>>>(partial, out);
}

// Round 10
// 22.869 us; speedup vs baseline: 1.1539x; 1.1539x over previous
//
#include <hip/hip_runtime.h>

// CRF log-likelihood: B=32, T=512, L=64.
// out = sum_b( -path_score[b] + log_Z[b] )
//
// Parallel-in-time forward scan via Birkhoff contraction (r5-proven
// geometry: 64 chunks/batch, CHUNK=8 real steps, BURN=8 from uniform;
// kappa<=~0.37/step -> ~2.5e-4 direction error at real-range entry;
// ~2016 boundaries -> worst-case ~0.5 vs threshold 1525).
// contrib = log(sum w)_end - log(sum w)_entry in a common scaling frame.
//
// Round-10 delta (single variable): pack 4 INDEPENDENT waves per block
// -> 512 WGs x 256 threads instead of 2048 WGs x 64, to isolate
// workgroup-dispatch overhead (~2.4 ns/WG implied by r9's slope). No
// LDS, no syncthreads, no fences; every cross-lane op is wave-scoped
// (ballot/shfl/readlane), so waves never interact.

#define CRF_B 32
#define CRF_T 512
#define CRF_L 64
#define NCHUNK 64
#define CHUNK 8               // CRF_T / NCHUNK
#define BURN 8
#define NSTEP (BURN + CHUNK)  // 16
#define NTASK (CRF_B * NCHUNK)   // 2048
#define WPB 4                 // independent waves per block
#define NBLK (NTASK / WPB)    // 512
#define LN2F 0.69314718055994530942f

__device__ __forceinline__ float bcast_lane(float v, int lane) {
    return __uint_as_float(
        (unsigned)__builtin_amdgcn_readlane((int)__float_as_uint(v), lane));
}

__device__ __forceinline__ float wave_sum(float v) {
#pragma unroll
    for (int off = 32; off; off >>= 1) v += __shfl_xor(v, off);
    return v;
}

// one matvec step: y_j = (sum_i w_i * E_ij) * eh
__device__ __forceinline__ float matvec_step(float wn, const float* E, float eh) {
    float acc[8];
#pragma unroll
    for (int q = 0; q < 8; ++q) acc[q] = 0.0f;
#pragma unroll
    for (int i = 0; i < CRF_L; ++i) {
        float wi = bcast_lane(wn, i);
        acc[i & 7] = fmaf(wi, E[i], acc[i & 7]);
    }
    float y = (((acc[0] + acc[1]) + (acc[2] + acc[3])) +
               ((acc[4] + acc[5]) + (acc[6] + acc[7])));
    return y * eh;
}

__device__ __forceinline__ float pow2_renorm(float wn) {  // exact, scale discarded
    unsigned w0 = (unsigned)__builtin_amdgcn_readfirstlane(
        (int)__float_as_uint(wn));
    int ex = (int)((w0 >> 23) & 0xffu) - 127;
    return ldexpf(wn, -ex);
}

__global__ __launch_bounds__(256, 1)
void crf_chunk_kernel(const float* __restrict__ inputs,
                      const float* __restrict__ labels,
                      const float* __restrict__ trans,
                      float* __restrict__ partial) {
    const int wid  = threadIdx.x >> 6;
    const int j    = threadIdx.x & 63;
    const int task = blockIdx.x * WPB + wid;  // 0..NTASK-1
    const int b = task >> 6;                  // / NCHUNK
    const int c = task & (NCHUNK - 1);

    const int r0     = c * CHUNK;
    const int base_h = (c == 0) ? 0 : (r0 - BURN);   // >= 0 (BURN == CHUNK)
    const int base_r = (c == 0) ? 0 : (r0 - 1);

    const float* inb = inputs + (size_t)b * CRF_T * CRF_L + j;
    const float* lab = labels + (size_t)b * CRF_T * CRF_L + j;

    // Stage h/r in registers; HBM latency hides under E-setup.
    float H[NSTEP];
#pragma unroll
    for (int s = 0; s < NSTEP; ++s) H[s] = inb[(base_h + s) * CRF_L];
    float R[CHUNK + 1];
#pragma unroll
    for (int s = 0; s <= CHUNK; ++s) R[s] = lab[(base_r + s) * CRF_L];

    // E column j resident in registers: E[i] = exp(trans[i][j])
    float E[CRF_L];
#pragma unroll
    for (int i = 0; i < CRF_L; ++i) {
        E[i] = __expf(trans[i * CRF_L + j]);
        asm volatile("" : "+v"(E[i]));
    }

    float wn, base2, hs = 0.0f, g = 0.0f;
    int prev_idx;

    if (c == 0) {
        // exact start at t=0; real steps t=1..CHUNK-1 (renorm-free)
        hs = H[0] * R[0];
        prev_idx = __ffsll(__ballot(R[0] > 0.5f)) - 1;
        wn = __expf(H[0]);
        base2 = 0.0f;
#pragma unroll
        for (int s = 1; s < CHUNK; ++s) {
            hs = fmaf(H[s], R[s], hs);
            int idx = __ffsll(__ballot(R[s] > 0.5f)) - 1;
            if (prev_idx == j) g += trans[j * CRF_L + idx];  // L1/L2-resident
            prev_idx = idx;
            wn = matvec_step(wn, E, __expf(H[s]));
        }
    } else {
        // burn-in from uniform: 8 steps, one mid renorm for overflow safety
        wn = 1.0f;
#pragma unroll
        for (int s = 0; s < BURN; ++s) {
            wn = matvec_step(wn, E, __expf(H[s]));
            if (s == 3) wn = pow2_renorm(wn);
        }
        wn = pow2_renorm(wn);                 // common frame for base2 & end
        base2 = __log2f(wave_sum(wn));
        prev_idx = __ffsll(__ballot(R[0] > 0.5f)) - 1;
        // real steps t = r0 .. r0+CHUNK-1 (renorm-free)
#pragma unroll
        for (int s = 0; s < CHUNK; ++s) {
            hs = fmaf(H[BURN + s], R[1 + s], hs);
            int idx = __ffsll(__ballot(R[1 + s] > 0.5f)) - 1;
            if (prev_idx == j) g += trans[j * CRF_L + idx];
            prev_idx = idx;
            wn = matvec_step(wn, E, __expf(H[BURN + s]));
        }
    }

    // ---- epilogue ----
    float ssum = wave_sum(wn);
    float path = wave_sum(hs + g);
    float contrib = (__log2f(ssum) - base2) * LN2F - path;
    if (j == 0) partial[task] = contrib;
}

__global__ __launch_bounds__(1024)
void crf_reduce_kernel(const float* __restrict__ partial, float* __restrict__ out) {
    const int tid = threadIdx.x;
    __shared__ float s[16];
    float v = partial[tid] + partial[tid + 1024];
    v = wave_sum(v);
    if ((tid & 63) == 0) s[tid >> 6] = v;
    __syncthreads();
    if (tid < 64) {
        float u = (tid < 16) ? s[tid] : 0.0f;
        u = wave_sum(u);
        if (tid == 0) out[0] = u;
    }
}

extern "C" void kernel_launch(void* const* d_in, const int* in_sizes, int n_in,
                              void* d_out, int out_size, void* d_ws, size_t ws_size,
                              hipStream_t stream) {
    const float* inputs = (const float*)d_in[0];
    const float* labels = (const float*)d_in[1];
    const float* trans  = (const float*)d_in[2];
    float* out = (float*)d_out;
    float* partial = (float*)d_ws;  // NTASK floats = 8 KB

    crf_chunk_kernel<<<NBLK, 256, 0, stream>>>(inputs, labels, trans, partial);
    crf_reduce_kernel<<<1, 1024, 0, stream>>>(partial, out);
}

// Round 12
// 22.195 us; speedup vs baseline: 1.1889x; 1.0303x over previous
//
#include <hip/hip_runtime.h>

// CRF log-likelihood: B=32, T=512, L=64.
// out = sum_b( -path_score[b] + log_Z[b] )
//
// Parallel-in-time forward scan via Birkhoff contraction (r5-proven
// geometry: 64 chunks/batch, CHUNK=8 real steps, BURN=8 from uniform;
// kappa<=~0.37/step -> ~2.5e-4 direction error at real-range entry;
// contrib = log(sum w)_end - log(sum w)_entry in a common scaling frame).
//
// Round-12 = round-11 with the writelane builtin (doesn't exist) replaced
// by a cndmask select chain (indices are wave-uniform SGPRs; j==s compare
// -> one v_cndmask_b32 per step, hoisted out of the scan loop).
//  - g-score fully hoisted: 9 ballots on pre-staged R[] -> per-lane select
//    -> ONE masked gather before the scan. (r5..r10 had a global load +
//    vmcnt wait INSIDE every scan step.)
//  - exp(h) precomputed for all steps (EH[]).
//  - inner FMA is inline-asm v_fmac_f32 with "s"(readlane(w)) and
//    "v"(E[i]) constraints -> forces E VGPR-resident (VGPR_Count=68 in
//    r5-r10 suggests E sat in AGPRs with an accvgpr_read per use).
// Scan body is now exactly: 64 v_readlane + 64 v_fmac + add-tree + 1 mul.

#define CRF_B 32
#define CRF_T 512
#define CRF_L 64
#define NCHUNK 64
#define CHUNK 8               // CRF_T / NCHUNK
#define BURN 8
#define NSTEP (BURN + CHUNK)  // 16
#define NTASK (CRF_B * NCHUNK)   // 2048
#define WPB 4                 // independent waves per block
#define NBLK (NTASK / WPB)    // 512
#define LN2F 0.69314718055994530942f

__device__ __forceinline__ float wave_sum(float v) {
#pragma unroll
    for (int off = 32; off; off >>= 1) v += __shfl_xor(v, off);
    return v;
}

// one matvec step: y_j = (sum_i w_i * E_ij) * eh
// readlane -> SGPR broadcast; v_fmac_f32 with SGPR src0 + VGPR src1.
__device__ __forceinline__ float matvec_step(float wn, const float* E, float eh) {
    float acc[8] = {0.f, 0.f, 0.f, 0.f, 0.f, 0.f, 0.f, 0.f};
    const int wb = __float_as_int(wn);
#pragma unroll
    for (int grp = 0; grp < 8; ++grp) {
        int w[8];
#pragma unroll
        for (int k = 0; k < 8; ++k)
            w[k] = __builtin_amdgcn_readlane(wb, grp * 8 + k);
#pragma unroll
        for (int k = 0; k < 8; ++k)
            asm("v_fmac_f32 %0, %1, %2"
                : "+v"(acc[k])
                : "s"(w[k]), "v"(E[grp * 8 + k]));
    }
    float y = (((acc[0] + acc[1]) + (acc[2] + acc[3])) +
               ((acc[4] + acc[5]) + (acc[6] + acc[7])));
    return y * eh;
}

__device__ __forceinline__ float pow2_renorm(float wn) {  // exact, scale discarded
    unsigned w0 = (unsigned)__builtin_amdgcn_readfirstlane(
        (int)__float_as_uint(wn));
    int ex = (int)((w0 >> 23) & 0xffu) - 127;
    return ldexpf(wn, -ex);
}

__global__ __launch_bounds__(256, 1)
void crf_chunk_kernel(const float* __restrict__ inputs,
                      const float* __restrict__ labels,
                      const float* __restrict__ trans,
                      float* __restrict__ partial) {
    const int wid  = threadIdx.x >> 6;
    const int j    = threadIdx.x & 63;
    const int task = blockIdx.x * WPB + wid;  // 0..NTASK-1
    const int b = task >> 6;                  // / NCHUNK
    const int c = task & (NCHUNK - 1);

    const int r0     = c * CHUNK;
    const int base_h = (c == 0) ? 0 : (r0 - BURN);   // >= 0 (BURN == CHUNK)
    const int base_r = (c == 0) ? 0 : (r0 - 1);

    const float* inb = inputs + (size_t)b * CRF_T * CRF_L + j;
    const float* lab = labels + (size_t)b * CRF_T * CRF_L + j;

    // Stage h/r in registers (independent loads, latency overlapped).
    float H[NSTEP];
#pragma unroll
    for (int s = 0; s < NSTEP; ++s) H[s] = inb[(base_h + s) * CRF_L];
    float R[CHUNK + 1];
#pragma unroll
    for (int s = 0; s <= CHUNK; ++s) R[s] = lab[(base_r + s) * CRF_L];

    // E column j resident in registers: E[i] = exp(trans[i][j])
    float E[CRF_L];
#pragma unroll
    for (int i = 0; i < CRF_L; ++i) {
        E[i] = __expf(trans[i * CRF_L + j]);
        asm volatile("" : "+v"(E[i]));
    }

    // Precompute all exp(h) off the critical path.
    float EH[NSTEP];
#pragma unroll
    for (int s = 0; s < NSTEP; ++s) EH[s] = __expf(H[s]);

    float wn, base2, hs = 0.0f, gv = 0.0f;

    if (c == 0) {
        // ---- hoisted path score: t = 0..7 ----
#pragma unroll
        for (int s = 0; s < CHUNK; ++s) hs = fmaf(H[s], R[s], hs);
        // transition pairs (t,t+1), t=0..6 -> lane t holds (idx_t, idx_{t+1})
        int vprev = 0, vcur = 0;
#pragma unroll
        for (int s = 0; s < CHUNK; ++s) {
            int idx = __ffsll(__ballot(R[s] > 0.5f)) - 1;  // wave-uniform
            if (s < CHUNK - 1) vprev = (j == s) ? idx : vprev;       // cndmask
            if (s > 0)         vcur  = (j == s - 1) ? idx : vcur;    // cndmask
        }
        if (j < CHUNK - 1) gv = trans[vprev * CRF_L + vcur];  // one masked gather

        // ---- exact scan from t=0; renorm-free ----
        wn = EH[0];
        base2 = 0.0f;
#pragma unroll
        for (int s = 1; s < CHUNK; ++s) wn = matvec_step(wn, E, EH[s]);
    } else {
        // ---- hoisted path score: t = r0..r0+7 ----
#pragma unroll
        for (int s = 0; s < CHUNK; ++s) hs = fmaf(H[BURN + s], R[1 + s], hs);
        // transition pairs use R[p],R[p+1], p=0..7 -> lane p
        int vprev = 0, vcur = 0;
#pragma unroll
        for (int s = 0; s <= CHUNK; ++s) {
            int idx = __ffsll(__ballot(R[s] > 0.5f)) - 1;  // wave-uniform
            if (s < CHUNK) vprev = (j == s) ? idx : vprev;           // cndmask
            if (s > 0)     vcur  = (j == s - 1) ? idx : vcur;        // cndmask
        }
        if (j < CHUNK) gv = trans[vprev * CRF_L + vcur];      // one masked gather

        // ---- burn-in from uniform (8 steps, one mid renorm) ----
        wn = 1.0f;
#pragma unroll
        for (int s = 0; s < BURN; ++s) {
            wn = matvec_step(wn, E, EH[s]);
            if (s == 3) wn = pow2_renorm(wn);
        }
        wn = pow2_renorm(wn);                 // common frame for base2 & end
        base2 = __log2f(wave_sum(wn));
        // ---- real steps, renorm-free ----
#pragma unroll
        for (int s = 0; s < CHUNK; ++s) wn = matvec_step(wn, E, EH[BURN + s]);
    }

    // ---- epilogue ----
    float ssum = wave_sum(wn);
    float path = wave_sum(hs + gv);
    float contrib = (__log2f(ssum) - base2) * LN2F - path;
    if (j == 0) partial[task] = contrib;
}

__global__ __launch_bounds__(1024)
void crf_reduce_kernel(const float* __restrict__ partial, float* __restrict__ out) {
    const int tid = threadIdx.x;
    __shared__ float s[16];
    float v = partial[tid] + partial[tid + 1024];
    v = wave_sum(v);
    if ((tid & 63) == 0) s[tid >> 6] = v;
    __syncthreads();
    if (tid < 64) {
        float u = (tid < 16) ? s[tid] : 0.0f;
        u = wave_sum(u);
        if (tid == 0) out[0] = u;
    }
}

extern "C" void kernel_launch(void* const* d_in, const int* in_sizes, int n_in,
                              void* d_out, int out_size, void* d_ws, size_t ws_size,
                              hipStream_t stream) {
    const float* inputs = (const float*)d_in[0];
    const float* labels = (const float*)d_in[1];
    const float* trans  = (const float*)d_in[2];
    float* out = (float*)d_out;
    float* partial = (float*)d_ws;  // NTASK floats = 8 KB

    crf_chunk_kernel<<<NBLK, 256, 0, stream>>>(inputs, labels, trans, partial);
    crf_reduce_kernel<<<1, 1024, 0, stream>>>(partial, out);
}